// Round 1
// baseline (4292.250 us; speedup 1.0000x reference)
//
#include <hip/hip_runtime.h>

#define NN 50000
#define EE 800000
#define INC 512
#define HIDC 128
#define OUTC 256

// C[M,Nc] = op(A)[M,K] * B[Nc,K]^T
// op(a)[m,k] = FUSE ? relu(a[m,k] + biask[k]) : a[m,k]
// B is torch-Linear layout [Nc, K] (row = output channel, contiguous in k).
// Tiles: BM=128, BN=64, BK=32. 256 threads, 8x4 micro-tile per thread.
template<bool FUSE>
__global__ __launch_bounds__(256) void sgemm_bt(
    const float* __restrict__ A, const float* __restrict__ B,
    const float* __restrict__ biask, float* __restrict__ C,
    int M, int Nc, int K)
{
    const int BK = 32;
    __shared__ float As[32][132];   // [k][m], pad 128->132 (16B-aligned rows)
    __shared__ float Bs[32][68];    // [k][n], pad 64->68

    int tid = threadIdx.x;
    int tx = tid & 15;          // 16 col-groups
    int ty = tid >> 4;          // 16 row-groups
    int row0 = blockIdx.x * 128;
    int col0 = blockIdx.y * 64;

    float acc[8][4];
#pragma unroll
    for (int i = 0; i < 8; i++)
#pragma unroll
        for (int j = 0; j < 4; j++) acc[i][j] = 0.f;

    for (int k0 = 0; k0 < K; k0 += BK) {
        // ---- load A tile 128x32 (transposed into As), 4 float4/thread ----
#pragma unroll
        for (int w = 0; w < 4; w++) {
            int f = tid + w * 256;       // 0..1023
            int r = f >> 3;              // 0..127
            int kq = f & 7;              // float4 index within the 32-wide k slab
            int grow = row0 + r;
            float4 v = make_float4(0.f, 0.f, 0.f, 0.f);
            if (grow < M)
                v = *(const float4*)&A[(long)grow * K + k0 + kq * 4];
            if (FUSE) {
                float4 bv = *(const float4*)&biask[k0 + kq * 4];
                v.x = fmaxf(v.x + bv.x, 0.f);
                v.y = fmaxf(v.y + bv.y, 0.f);
                v.z = fmaxf(v.z + bv.z, 0.f);
                v.w = fmaxf(v.w + bv.w, 0.f);
                // note: padded rows (grow>=M) become relu(bias) but only feed
                // acc of those same (guarded) rows -> never stored.
            }
            As[kq * 4 + 0][r] = v.x;
            As[kq * 4 + 1][r] = v.y;
            As[kq * 4 + 2][r] = v.z;
            As[kq * 4 + 3][r] = v.w;
        }
        // ---- load B tile 64x32 (transposed into Bs), 2 float4/thread ----
#pragma unroll
        for (int w = 0; w < 2; w++) {
            int f = tid + w * 256;       // 0..511
            int r = f >> 3;              // 0..63
            int kq = f & 7;
            float4 v = *(const float4*)&B[(long)(col0 + r) * K + k0 + kq * 4];
            Bs[kq * 4 + 0][r] = v.x;
            Bs[kq * 4 + 1][r] = v.y;
            Bs[kq * 4 + 2][r] = v.z;
            Bs[kq * 4 + 3][r] = v.w;
        }
        __syncthreads();

        // ---- compute: per kk, 3 x ds_read_b128 + 32 v_fma_f32 ----
#pragma unroll
        for (int kk = 0; kk < BK; kk++) {
            float4 a0 = *(const float4*)&As[kk][ty * 8];
            float4 a1 = *(const float4*)&As[kk][ty * 8 + 4];
            float4 b0 = *(const float4*)&Bs[kk][tx * 4];
            float av[8] = {a0.x, a0.y, a0.z, a0.w, a1.x, a1.y, a1.z, a1.w};
            float bv[4] = {b0.x, b0.y, b0.z, b0.w};
#pragma unroll
            for (int i = 0; i < 8; i++)
#pragma unroll
                for (int j = 0; j < 4; j++)
                    acc[i][j] = fmaf(av[i], bv[j], acc[i][j]);
        }
        __syncthreads();
    }

    // ---- store, float4 per row, coalesced over tx ----
#pragma unroll
    for (int i = 0; i < 8; i++) {
        int grow = row0 + ty * 8 + i;
        if (grow < M) {
            float4 o = make_float4(acc[i][0], acc[i][1], acc[i][2], acc[i][3]);
            *(float4*)&C[(long)grow * Nc + col0 + tx * 4] = o;
        }
    }
}

// out[dst] += h[src], float4 per thread, LOGC4 = log2(channels/4)
template<int LOGC4>
__global__ __launch_bounds__(256) void scatter_f4(
    const float* __restrict__ h, const int* __restrict__ ei,
    float* __restrict__ out)
{
    const int C4 = 1 << LOGC4;
    const int Cc = C4 * 4;
    long gid = (long)blockIdx.x * 256 + threadIdx.x;
    if (gid >= (long)EE * C4) return;
    int e = (int)(gid >> LOGC4);
    int c4 = (int)(gid & (C4 - 1));
    int src = ei[e];
    int dst = ei[EE + e];
    float4 v = *(const float4*)&h[(long)src * Cc + c4 * 4];
    float* o = &out[(long)dst * Cc + c4 * 4];
    atomicAdd(o + 0, v.x);
    atomicAdd(o + 1, v.y);
    atomicAdd(o + 2, v.z);
    atomicAdd(o + 3, v.w);
}

// out[n, c] = b2[c]  (d_out is poisoned 0xAA before every launch)
__global__ __launch_bounds__(256) void init_out(
    float* __restrict__ out, const float* __restrict__ b2)
{
    int gid = blockIdx.x * 256 + threadIdx.x;   // over N*OUTC/4 float4s
    if (gid >= NN * (OUTC / 4)) return;
    int c4 = gid & (OUTC / 4 - 1);              // OUTC/4 = 64 (pow2)
    ((float4*)out)[gid] = ((const float4*)b2)[c4];
}

extern "C" void kernel_launch(void* const* d_in, const int* in_sizes, int n_in,
                              void* d_out, int out_size, void* d_ws, size_t ws_size,
                              hipStream_t stream) {
    const float* x  = (const float*)d_in[0];
    const int*   ei = (const int*)d_in[1];
    const float* w1 = (const float*)d_in[2];
    const float* b1 = (const float*)d_in[3];
    const float* w2 = (const float*)d_in[4];
    const float* b2 = (const float*)d_in[5];
    float* out = (float*)d_out;

    char* ws = (char*)d_ws;
    float* agg1 = (float*)ws;                              // [N,128] 25.6 MB
    float* h    = (float*)(ws + (size_t)NN * HIDC * 4);    // [N,128] 25.6 MB
    float* h2   = (float*)(ws + (size_t)NN * HIDC * 4);    // [N,256] overlaps h (h dead by then)

    // agg1 must start at zero every call (ws is re-poisoned to 0xAA)
    hipMemsetAsync(agg1, 0, (size_t)NN * HIDC * 4, stream);

    dim3 blk(256);
    int mblk = (NN + 127) / 128;   // 391

    // h = x @ w1^T            [50000,512] x [512,128]
    sgemm_bt<false><<<dim3(mblk, HIDC / 64), blk, 0, stream>>>(
        x, w1, nullptr, h, NN, HIDC, INC);

    // agg1[dst] += h[src]     (E x 32 float4-threads)
    {
        long total = (long)EE * (HIDC / 4);
        scatter_f4<5><<<dim3((unsigned)((total + 255) / 256)), blk, 0, stream>>>(h, ei, agg1);
    }

    // out = broadcast(b2)
    init_out<<<dim3((NN * (OUTC / 4) + 255) / 256), blk, 0, stream>>>(out, b2);

    // h2 = relu(agg1 + b1) @ w2^T     [50000,128] x [128,256]
    sgemm_bt<true><<<dim3(mblk, OUTC / 64), blk, 0, stream>>>(
        agg1, w2, b1, h2, NN, OUTC, HIDC);

    // out[dst] += h2[src]     (E x 64 float4-threads)
    {
        long total = (long)EE * (OUTC / 4);
        scatter_f4<6><<<dim3((unsigned)((total + 255) / 256)), blk, 0, stream>>>(h2, ei, out);
    }
}

// Round 2
// 513.409 us; speedup vs baseline: 8.3603x; 8.3603x over previous
//
#include <hip/hip_runtime.h>

#define NN 50000
#define EE 800000
#define INC 512
#define HIDC 128
#define OUTC 256
#define BUCKET_CAP 64
#define OV_CAP 65536

// ---------------- GEMM: C[M,Nc] = op(A)[M,K] * B[Nc,K]^T ----------------
// op(a)[m,k] = FUSE ? relu(a[m,k] + biask[k]) : a[m,k]
// Tiles: BM=128, BN=64, BK=32. 256 threads, 8x4 micro-tile per thread.
template<bool FUSE>
__global__ __launch_bounds__(256) void sgemm_bt(
    const float* __restrict__ A, const float* __restrict__ B,
    const float* __restrict__ biask, float* __restrict__ C,
    int M, int Nc, int K)
{
    const int BK = 32;
    __shared__ float As[32][132];   // [k][m]
    __shared__ float Bs[32][68];    // [k][n]

    int tid = threadIdx.x;
    int tx = tid & 15;
    int ty = tid >> 4;
    int row0 = blockIdx.x * 128;
    int col0 = blockIdx.y * 64;

    float acc[8][4];
#pragma unroll
    for (int i = 0; i < 8; i++)
#pragma unroll
        for (int j = 0; j < 4; j++) acc[i][j] = 0.f;

    for (int k0 = 0; k0 < K; k0 += BK) {
#pragma unroll
        for (int w = 0; w < 4; w++) {
            int f = tid + w * 256;
            int r = f >> 3;
            int kq = f & 7;
            int grow = row0 + r;
            float4 v = make_float4(0.f, 0.f, 0.f, 0.f);
            if (grow < M)
                v = *(const float4*)&A[(long)grow * K + k0 + kq * 4];
            if (FUSE) {
                float4 bv = *(const float4*)&biask[k0 + kq * 4];
                v.x = fmaxf(v.x + bv.x, 0.f);
                v.y = fmaxf(v.y + bv.y, 0.f);
                v.z = fmaxf(v.z + bv.z, 0.f);
                v.w = fmaxf(v.w + bv.w, 0.f);
            }
            As[kq * 4 + 0][r] = v.x;
            As[kq * 4 + 1][r] = v.y;
            As[kq * 4 + 2][r] = v.z;
            As[kq * 4 + 3][r] = v.w;
        }
#pragma unroll
        for (int w = 0; w < 2; w++) {
            int f = tid + w * 256;
            int r = f >> 3;
            int kq = f & 7;
            float4 v = *(const float4*)&B[(long)(col0 + r) * K + k0 + kq * 4];
            Bs[kq * 4 + 0][r] = v.x;
            Bs[kq * 4 + 1][r] = v.y;
            Bs[kq * 4 + 2][r] = v.z;
            Bs[kq * 4 + 3][r] = v.w;
        }
        __syncthreads();

#pragma unroll
        for (int kk = 0; kk < BK; kk++) {
            float4 a0 = *(const float4*)&As[kk][ty * 8];
            float4 a1 = *(const float4*)&As[kk][ty * 8 + 4];
            float4 b0 = *(const float4*)&Bs[kk][tx * 4];
            float av[8] = {a0.x, a0.y, a0.z, a0.w, a1.x, a1.y, a1.z, a1.w};
            float bv[4] = {b0.x, b0.y, b0.z, b0.w};
#pragma unroll
            for (int i = 0; i < 8; i++)
#pragma unroll
                for (int j = 0; j < 4; j++)
                    acc[i][j] = fmaf(av[i], bv[j], acc[i][j]);
        }
        __syncthreads();
    }

#pragma unroll
    for (int i = 0; i < 8; i++) {
        int grow = row0 + ty * 8 + i;
        if (grow < M) {
            float4 o = make_float4(acc[i][0], acc[i][1], acc[i][2], acc[i][3]);
            *(float4*)&C[(long)grow * Nc + col0 + tx * 4] = o;
        }
    }
}

// ---------------- bucket build: per-dst edge lists, capacity 64 ----------
__global__ __launch_bounds__(256) void build_buckets(
    const int* __restrict__ ei, int* __restrict__ cnt,
    int* __restrict__ bucket, int* __restrict__ ovcnt,
    int* __restrict__ ovlist)
{
    int e = blockIdx.x * 256 + threadIdx.x;
    if (e >= EE) return;
    int src = ei[e];
    int dst = ei[EE + e];
    int pos = atomicAdd(&cnt[dst], 1);
    if (pos < BUCKET_CAP) {
        bucket[dst * BUCKET_CAP + pos] = src;
    } else {
        int o = atomicAdd(ovcnt, 1);
        if (o < OV_CAP) { ovlist[o * 2] = src; ovlist[o * 2 + 1] = dst; }
    }
}

// ---------------- segmented gather-sum: out[n] = sum_{e->n} h[src_e] (+bias)
// LOGC4: log2(C/4). C=128 -> 5 (8 nodes/block), C=256 -> 6 (4 nodes/block).
template<int LOGC4, bool ADDB>
__global__ __launch_bounds__(256) void seg_gather(
    const float* __restrict__ h, const int* __restrict__ bucket,
    const int* __restrict__ cnt, const float* __restrict__ bias,
    float* __restrict__ out)
{
    const int C4 = 1 << LOGC4;        // float4s per row
    const int NPB = 256 >> LOGC4;     // nodes per block
    int t = threadIdx.x;
    int node = blockIdx.x * NPB + (t >> LOGC4);
    int c4 = t & (C4 - 1);
    if (node >= NN) return;
    int m = cnt[node];
    if (m > BUCKET_CAP) m = BUCKET_CAP;
    const int* bk = bucket + node * BUCKET_CAP;
    float4 acc = make_float4(0.f, 0.f, 0.f, 0.f);
    for (int j = 0; j < m; j++) {
        int src = bk[j];
        float4 v = *(const float4*)&h[((long)src << (LOGC4 + 2)) + c4 * 4];
        acc.x += v.x; acc.y += v.y; acc.z += v.z; acc.w += v.w;
    }
    if (ADDB) {
        float4 bv = *(const float4*)&bias[c4 * 4];
        acc.x += bv.x; acc.y += bv.y; acc.z += bv.z; acc.w += bv.w;
    }
    *(float4*)&out[((long)node << (LOGC4 + 2)) + c4 * 4] = acc;
}

// ---------------- overflow fallback (expected count: 0) ------------------
template<int LOGC4>
__global__ __launch_bounds__(256) void overflow_fix(
    const float* __restrict__ h, const int* __restrict__ ovcnt,
    const int* __restrict__ ovlist, float* __restrict__ out)
{
    int n = *ovcnt;
    if (n > OV_CAP) n = OV_CAP;
    const int C = 4 << LOGC4;
    for (int i = 0; i < n; i++) {
        int src = ovlist[i * 2];
        int dst = ovlist[i * 2 + 1];
        for (int c = threadIdx.x; c < C; c += 256)
            atomicAdd(&out[(long)dst * C + c], h[(long)src * C + c]);
    }
}

extern "C" void kernel_launch(void* const* d_in, const int* in_sizes, int n_in,
                              void* d_out, int out_size, void* d_ws, size_t ws_size,
                              hipStream_t stream) {
    const float* x  = (const float*)d_in[0];
    const int*   ei = (const int*)d_in[1];
    const float* w1 = (const float*)d_in[2];
    const float* b1 = (const float*)d_in[3];
    const float* w2 = (const float*)d_in[4];
    const float* b2 = (const float*)d_in[5];
    float* out = (float*)d_out;

    char* ws = (char*)d_ws;
    size_t off = 0;
    float* agg1 = (float*)(ws + off); off += (size_t)NN * HIDC * 4;       // 25.6 MB
    float* h    = (float*)(ws + off);                                     // 25.6 MB
    float* h2   = (float*)(ws + off); off += (size_t)NN * OUTC * 4;       // 51.2 MB (overlaps h; h dead by then)
    int* bucket = (int*)(ws + off);   off += (size_t)NN * BUCKET_CAP * 4; // 12.8 MB
    int* cnt    = (int*)(ws + off);   off += (size_t)NN * 4;              // 0.2 MB
    int* ovcnt  = (int*)(ws + off);   off += 256;
    int* ovlist = (int*)(ws + off);   off += (size_t)OV_CAP * 2 * 4;      // 0.5 MB

    dim3 blk(256);
    int mblk = (NN + 127) / 128;   // 391

    // zero the bucket counters + overflow counter (ws re-poisoned each call)
    hipMemsetAsync(cnt, 0, (size_t)NN * 4, stream);
    hipMemsetAsync(ovcnt, 0, 4, stream);

    // build per-destination buckets (used by both layers)
    build_buckets<<<dim3((EE + 255) / 256), blk, 0, stream>>>(ei, cnt, bucket, ovcnt, ovlist);

    // h = x @ w1^T            [50000,512] x [512,128]
    sgemm_bt<false><<<dim3(mblk, HIDC / 64), blk, 0, stream>>>(
        x, w1, nullptr, h, NN, HIDC, INC);

    // agg1[n] = sum over in-edges of h[src]
    seg_gather<5, false><<<dim3((NN + 7) / 8), blk, 0, stream>>>(h, bucket, cnt, nullptr, agg1);
    overflow_fix<5><<<dim3(1), blk, 0, stream>>>(h, ovcnt, ovlist, agg1);

    // h2 = relu(agg1 + b1) @ w2^T     [50000,128] x [128,256]
    sgemm_bt<true><<<dim3(mblk, OUTC / 64), blk, 0, stream>>>(
        agg1, w2, b1, h2, NN, OUTC, HIDC);

    // out[n] = sum over in-edges of h2[src] + b2
    seg_gather<6, true><<<dim3((NN + 3) / 4), blk, 0, stream>>>(h2, bucket, cnt, b2, out);
    overflow_fix<6><<<dim3(1), blk, 0, stream>>>(h2, ovcnt, ovlist, out);
}

// Round 3
// 398.664 us; speedup vs baseline: 10.7666x; 1.2878x over previous
//
#include <hip/hip_runtime.h>

#define NN 50000
#define EE 800000
#define INC 512
#define HIDC 128
#define OUTC 256
#define BUCKET_CAP 64
#define OV_CAP 65536

typedef __attribute__((ext_vector_type(8))) short bf16x8;
typedef __attribute__((ext_vector_type(4))) float f32x4;

__device__ __forceinline__ short f2bf(float f) {
    unsigned u = __float_as_uint(f);
    unsigned r = u + 0x7fff + ((u >> 16) & 1);   // RNE to bf16
    return (short)(r >> 16);
}
__device__ __forceinline__ float bf2f(short s) {
    return __uint_as_float(((unsigned)(unsigned short)s) << 16);
}

// ---------------------------------------------------------------------------
// MFMA GEMM: C[M,Nc] = A[M,K] * B[Nc,K]^T (+bias), A,B fp32 in global,
// converted to bf16 during LDS staging. BM=128, BN=128, BK=64.
// 256 threads = 4 waves, each wave computes a 64x64 sub-tile (4x4 MFMA 16x16x32).
// OUT_BF16: store C as bf16 (for gather consumption); else fp32.
// Verified layouts (guide §3): A-frag A[m=lane&15][k=quad*8+j];
// B-frag B[n=lane&15][k=quad*8+j]; C/D col=lane&15, row=quad*4+reg.
template<bool ADDBIAS, bool OUT_BF16>
__global__ __launch_bounds__(256) void mfma_gemm(
    const float* __restrict__ A, const float* __restrict__ B,
    const float* __restrict__ bias, void* __restrict__ Cv,
    int M, int Nc, int K)
{
    __shared__ short As[128][72];   // [m][k], +8 pad: b128 reads land 2-way max
    __shared__ short Bs[128][72];   // [n][k]

    int tid = threadIdx.x;
    int lane = tid & 63;
    int wave = tid >> 6;
    int row0 = blockIdx.x * 128;
    int col0 = blockIdx.y * 128;
    int wm = (wave & 1) * 64;
    int wn = (wave >> 1) * 64;
    int l16 = lane & 15;
    int quad = lane >> 4;

    f32x4 acc[4][4];
#pragma unroll
    for (int i = 0; i < 4; i++)
#pragma unroll
        for (int j = 0; j < 4; j++) acc[i][j] = {0.f, 0.f, 0.f, 0.f};

    for (int k0 = 0; k0 < K; k0 += 64) {
        // ---- stage A tile 128x64 fp32 -> bf16 (8 float4 per thread) ----
#pragma unroll
        for (int w = 0; w < 8; w++) {
            int f = tid + w * 256;     // 0..2047 float4 slots (16 per row)
            int r = f >> 4;
            int c4 = f & 15;
            int gr = row0 + r;
            float4 v = make_float4(0.f, 0.f, 0.f, 0.f);
            if (gr < M) v = *(const float4*)&A[(long)gr * K + k0 + c4 * 4];
            short4 s;
            s.x = f2bf(v.x); s.y = f2bf(v.y); s.z = f2bf(v.z); s.w = f2bf(v.w);
            *(short4*)&As[r][c4 * 4] = s;
        }
        // ---- stage B tile 128x64 (rows col0..col0+127 of B[Nc,K]) ----
#pragma unroll
        for (int w = 0; w < 8; w++) {
            int f = tid + w * 256;
            int r = f >> 4;
            int c4 = f & 15;
            float4 v = *(const float4*)&B[(long)(col0 + r) * K + k0 + c4 * 4];
            short4 s;
            s.x = f2bf(v.x); s.y = f2bf(v.y); s.z = f2bf(v.z); s.w = f2bf(v.w);
            *(short4*)&Bs[r][c4 * 4] = s;
        }
        __syncthreads();

#pragma unroll
        for (int kk = 0; kk < 64; kk += 32) {
            bf16x8 af[4], bfr[4];
#pragma unroll
            for (int i = 0; i < 4; i++)
                af[i] = *(const bf16x8*)&As[wm + i * 16 + l16][kk + quad * 8];
#pragma unroll
            for (int j = 0; j < 4; j++)
                bfr[j] = *(const bf16x8*)&Bs[wn + j * 16 + l16][kk + quad * 8];
#pragma unroll
            for (int i = 0; i < 4; i++)
#pragma unroll
                for (int j = 0; j < 4; j++)
                    acc[i][j] = __builtin_amdgcn_mfma_f32_16x16x32_bf16(
                        af[i], bfr[j], acc[i][j], 0, 0, 0);
        }
        __syncthreads();
    }

    // ---- epilogue ----
#pragma unroll
    for (int i = 0; i < 4; i++) {
#pragma unroll
        for (int r = 0; r < 4; r++) {
            int grow = row0 + wm + i * 16 + quad * 4 + r;
            if (grow < M) {
#pragma unroll
                for (int j = 0; j < 4; j++) {
                    int gcol = col0 + wn + j * 16 + l16;
                    float v = acc[i][j][r];
                    if (ADDBIAS) v += bias[gcol];
                    if (OUT_BF16)
                        ((short*)Cv)[(long)grow * Nc + gcol] = f2bf(v);
                    else
                        ((float*)Cv)[(long)grow * Nc + gcol] = v;
                }
            }
        }
    }
}

// ---------------- bucket build: per-dst edge lists, capacity 64 ----------
__global__ __launch_bounds__(256) void build_buckets(
    const int* __restrict__ ei, int* __restrict__ cnt,
    int* __restrict__ bucket, int* __restrict__ ovcnt,
    int* __restrict__ ovlist)
{
    int e = blockIdx.x * 256 + threadIdx.x;
    if (e >= EE) return;
    int src = ei[e];
    int dst = ei[EE + e];
    int pos = atomicAdd(&cnt[dst], 1);
    if (pos < BUCKET_CAP) {
        bucket[dst * BUCKET_CAP + pos] = src;
    } else {
        int o = atomicAdd(ovcnt, 1);
        if (o < OV_CAP) { ovlist[o * 2] = src; ovlist[o * 2 + 1] = dst; }
    }
}

// ---- segmented gather-sum over bf16 rows, C=128: out[n] = sum h[src] (fp32)
__global__ __launch_bounds__(256) void gather_bf16_c128(
    const short* __restrict__ h, const int* __restrict__ bucket,
    const int* __restrict__ cnt, float* __restrict__ outp)
{
    int t = threadIdx.x;
    int node = blockIdx.x * 8 + (t >> 5);   // 8 nodes/block
    int c4 = t & 31;                        // 32 x short4 covers 128 ch
    if (node >= NN) return;
    int m = cnt[node];
    if (m > BUCKET_CAP) m = BUCKET_CAP;
    const int* bk = bucket + node * BUCKET_CAP;
    float4 acc = make_float4(0.f, 0.f, 0.f, 0.f);
    for (int j = 0; j < m; j++) {
        int src = bk[j];
        short4 v = *(const short4*)&h[((long)src << 7) + c4 * 4];
        acc.x += bf2f(v.x); acc.y += bf2f(v.y);
        acc.z += bf2f(v.z); acc.w += bf2f(v.w);
    }
    *(float4*)&outp[((long)node << 7) + c4 * 4] = acc;
}

// ---- r = bf16(relu(agg1 + b1)), C=128 --------------------------------------
__global__ __launch_bounds__(256) void relu_bias_pack(
    const float* __restrict__ agg1, const float* __restrict__ b1,
    short* __restrict__ r)
{
    int gid = blockIdx.x * 256 + threadIdx.x;   // over N*32 float4s
    if (gid >= NN * 32) return;
    int c4 = gid & 31;
    float4 v = ((const float4*)agg1)[gid];
    float4 b = ((const float4*)b1)[c4];
    short4 s;
    s.x = f2bf(fmaxf(v.x + b.x, 0.f));
    s.y = f2bf(fmaxf(v.y + b.y, 0.f));
    s.z = f2bf(fmaxf(v.z + b.z, 0.f));
    s.w = f2bf(fmaxf(v.w + b.w, 0.f));
    ((short4*)r)[gid] = s;
}

// ---------------- overflow fallbacks (expected count: 0) -------------------
__global__ __launch_bounds__(256) void ov_fix1(
    const short* __restrict__ h, const int* __restrict__ ovcnt,
    const int* __restrict__ ovlist, float* __restrict__ agg1)
{
    int n = *ovcnt; if (n > OV_CAP) n = OV_CAP;
    for (int i = 0; i < n; i++) {
        int src = ovlist[i * 2], dst = ovlist[i * 2 + 1];
        for (int c = threadIdx.x; c < HIDC; c += 256)
            atomicAdd(&agg1[(long)dst * HIDC + c], bf2f(h[(long)src * HIDC + c]));
    }
}
__global__ __launch_bounds__(256) void ov_fix2(
    const float* __restrict__ agg1, const float* __restrict__ b1,
    const int* __restrict__ ovcnt, const int* __restrict__ ovlist,
    float* __restrict__ agg2)
{
    int n = *ovcnt; if (n > OV_CAP) n = OV_CAP;
    for (int i = 0; i < n; i++) {
        int src = ovlist[i * 2], dst = ovlist[i * 2 + 1];
        for (int c = threadIdx.x; c < HIDC; c += 256)
            atomicAdd(&agg2[(long)dst * HIDC + c],
                      fmaxf(agg1[(long)src * HIDC + c] + b1[c], 0.f));
    }
}

extern "C" void kernel_launch(void* const* d_in, const int* in_sizes, int n_in,
                              void* d_out, int out_size, void* d_ws, size_t ws_size,
                              hipStream_t stream) {
    const float* x  = (const float*)d_in[0];
    const int*   ei = (const int*)d_in[1];
    const float* w1 = (const float*)d_in[2];
    const float* b1 = (const float*)d_in[3];
    const float* w2 = (const float*)d_in[4];
    const float* b2 = (const float*)d_in[5];
    float* out = (float*)d_out;

    char* ws = (char*)d_ws;
    size_t off = 0;
    short* h    = (short*)(ws + off); off += (size_t)NN * HIDC * 2;        // 12.8 MB bf16
    float* agg1 = (float*)(ws + off); off += (size_t)NN * HIDC * 4;        // 25.6 MB
    short* r    = (short*)(ws + off); off += (size_t)NN * HIDC * 2;        // 12.8 MB bf16
    float* agg2 = (float*)(ws + off); off += (size_t)NN * HIDC * 4;        // 25.6 MB
    int* bucket = (int*)(ws + off);   off += (size_t)NN * BUCKET_CAP * 4;  // 12.8 MB
    int* cnt    = (int*)(ws + off);   off += (size_t)NN * 4;               // 0.2 MB
    int* ovcnt  = (int*)(ws + off);   off += 256;
    int* ovlist = (int*)(ws + off);   off += (size_t)OV_CAP * 2 * 4;       // 0.5 MB

    dim3 blk(256);
    int mblk = (NN + 127) / 128;   // 391

    hipMemsetAsync(cnt, 0, (size_t)NN * 4, stream);
    hipMemsetAsync(ovcnt, 0, 4, stream);

    build_buckets<<<dim3((EE + 255) / 256), blk, 0, stream>>>(ei, cnt, bucket, ovcnt, ovlist);

    // h = bf16(x @ w1^T)        [50000,512] x [512,128] -> bf16
    mfma_gemm<false, true><<<dim3(mblk, 1), blk, 0, stream>>>(
        x, w1, nullptr, h, NN, HIDC, INC);

    // agg1 = A * h              (fp32 accumulate)
    gather_bf16_c128<<<dim3((NN + 7) / 8), blk, 0, stream>>>(h, bucket, cnt, agg1);
    ov_fix1<<<dim3(1), blk, 0, stream>>>(h, ovcnt, ovlist, agg1);

    // r = bf16(relu(agg1 + b1))
    relu_bias_pack<<<dim3((NN * 32 + 255) / 256), blk, 0, stream>>>(agg1, b1, r);

    // agg2 = A * r              (fp32 accumulate)
    gather_bf16_c128<<<dim3((NN + 7) / 8), blk, 0, stream>>>(r, bucket, cnt, agg2);
    ov_fix2<<<dim3(1), blk, 0, stream>>>(agg1, b1, ovcnt, ovlist, agg2);

    // out = agg2 @ w2^T + b2    [50000,128] x [128,256] -> fp32
    mfma_gemm<true, false><<<dim3(mblk, OUTC / 128), blk, 0, stream>>>(
        agg2, w2, b2, out, NN, OUTC, HIDC);
}

// Round 4
// 306.016 us; speedup vs baseline: 14.0262x; 1.3028x over previous
//
#include <hip/hip_runtime.h>

#define NN 50000
#define EE 800000
#define INC 512
#define HIDC 128
#define OUTC 256
#define CAP 64
#define OV_CAP 65536
#define BUILD_BLOCKS 196      // ceil(800000 / (256*16))
#define GB1 782               // ceil(NN/64)

typedef __attribute__((ext_vector_type(8))) short bf16x8;
typedef __attribute__((ext_vector_type(4))) float f32x4;

__device__ __forceinline__ short f2bf(float f) {
    unsigned u = __float_as_uint(f);
    unsigned r = u + 0x7fff + ((u >> 16) & 1);   // RNE to bf16
    return (short)(r >> 16);
}
__device__ __forceinline__ float bf2f(short s) {
    return __uint_as_float(((unsigned)(unsigned short)s) << 16);
}

// ---------------------------------------------------------------------------
// GEMM core: C[M,Nc] = A[M,K] * B[Nc,K]^T (+bias). BM=64, BN=128, BK=64.
// 256 threads = 4 waves; wave computes 32x64 (2x4 tiles of 16x16x32 MFMA).
// A fp32 (converted during staging) or bf16; B fp32 (w1/w2). Verified layouts:
// A-frag A[m=lane&15][k=quad*8+j]; C/D col=lane&15, row=quad*4+reg.
template<bool IN_BF16, bool ADDBIAS, bool OUT_BF16>
__device__ __forceinline__ void gemm_core(
    const void* __restrict__ Av, const float* __restrict__ B,
    const float* __restrict__ bias, void* __restrict__ Cv,
    int M, int Nc, int K, int bx, int by,
    short As[64][72], short Bs[128][72])
{
    int tid = threadIdx.x;
    int lane = tid & 63, wave = tid >> 6;
    int row0 = bx * 64, col0 = by * 128;
    int wm = (wave & 1) * 32, wn = (wave >> 1) * 64;
    int l16 = lane & 15, quad = lane >> 4;

    f32x4 acc[2][4];
#pragma unroll
    for (int i = 0; i < 2; i++)
#pragma unroll
        for (int j = 0; j < 4; j++) acc[i][j] = {0.f, 0.f, 0.f, 0.f};

    for (int k0 = 0; k0 < K; k0 += 64) {
        // ---- stage A tile 64x64 ----
        if (IN_BF16) {
            const short* A = (const short*)Av;
#pragma unroll
            for (int w = 0; w < 2; w++) {
                int f = tid + w * 256;          // 512 x 16B slots
                int rr = f >> 3, c8 = f & 7;
                int gr = row0 + rr;
                bf16x8 v = {0, 0, 0, 0, 0, 0, 0, 0};
                if (gr < M) v = *(const bf16x8*)&A[(long)gr * K + k0 + c8 * 8];
                *(bf16x8*)&As[rr][c8 * 8] = v;
            }
        } else {
            const float* A = (const float*)Av;
#pragma unroll
            for (int w = 0; w < 4; w++) {
                int f = tid + w * 256;          // 1024 x float4 slots
                int rr = f >> 4, c4 = f & 15;
                int gr = row0 + rr;
                float4 v = make_float4(0.f, 0.f, 0.f, 0.f);
                if (gr < M) v = *(const float4*)&A[(long)gr * K + k0 + c4 * 4];
                short4 s;
                s.x = f2bf(v.x); s.y = f2bf(v.y); s.z = f2bf(v.z); s.w = f2bf(v.w);
                *(short4*)&As[rr][c4 * 4] = s;
            }
        }
        // ---- stage B tile 128x64 (fp32 -> bf16) ----
#pragma unroll
        for (int w = 0; w < 8; w++) {
            int f = tid + w * 256;              // 2048 x float4 slots
            int rr = f >> 4, c4 = f & 15;
            float4 v = *(const float4*)&B[(long)(col0 + rr) * K + k0 + c4 * 4];
            short4 s;
            s.x = f2bf(v.x); s.y = f2bf(v.y); s.z = f2bf(v.z); s.w = f2bf(v.w);
            *(short4*)&Bs[rr][c4 * 4] = s;
        }
        __syncthreads();

#pragma unroll
        for (int kk = 0; kk < 64; kk += 32) {
            bf16x8 af[2], bfr[4];
#pragma unroll
            for (int i = 0; i < 2; i++)
                af[i] = *(const bf16x8*)&As[wm + i * 16 + l16][kk + quad * 8];
#pragma unroll
            for (int j = 0; j < 4; j++)
                bfr[j] = *(const bf16x8*)&Bs[wn + j * 16 + l16][kk + quad * 8];
#pragma unroll
            for (int i = 0; i < 2; i++)
#pragma unroll
                for (int j = 0; j < 4; j++)
                    acc[i][j] = __builtin_amdgcn_mfma_f32_16x16x32_bf16(
                        af[i], bfr[j], acc[i][j], 0, 0, 0);
        }
        __syncthreads();
    }

    // ---- epilogue ----
#pragma unroll
    for (int i = 0; i < 2; i++) {
#pragma unroll
        for (int rr = 0; rr < 4; rr++) {
            int grow = row0 + wm + i * 16 + quad * 4 + rr;
            if (grow < M) {
#pragma unroll
                for (int j = 0; j < 4; j++) {
                    int gcol = col0 + wn + j * 16 + l16;
                    float v = acc[i][j][rr];
                    if (ADDBIAS) v += bias[gcol];
                    if (OUT_BF16)
                        ((short*)Cv)[(long)grow * Nc + gcol] = f2bf(v);
                    else
                        ((float*)Cv)[(long)grow * Nc + gcol] = v;
                }
            }
        }
    }
}

// ---------------------------------------------------------------------------
// Fat kernel: blocks [0,BUILD_BLOCKS) build dst-buckets; the rest run gemm1.
// The two jobs starve different resources (random-line writes vs BW/MFMA).
__global__ __launch_bounds__(256) void fat_build_gemm1(
    const int* __restrict__ ei, int* __restrict__ cnt,
    unsigned short* __restrict__ bucket, int* __restrict__ ovcnt,
    int* __restrict__ ovlist,
    const float* __restrict__ x, const float* __restrict__ w1,
    short* __restrict__ h)
{
    __shared__ short As[64][72];
    __shared__ short Bs[128][72];

    if (blockIdx.x < BUILD_BLOCKS) {
        int t = threadIdx.x;
        long base = ((long)blockIdx.x * 256 + t) * 16;
        if (base + 16 <= EE) {
            int4 sv[4], dv[4];
#pragma unroll
            for (int q = 0; q < 4; q++) {
                sv[q] = *(const int4*)&ei[base + q * 4];
                dv[q] = *(const int4*)&ei[EE + base + q * 4];
            }
            const int* sp = (const int*)sv;
            const int* dp = (const int*)dv;
#pragma unroll
            for (int k = 0; k < 16; k++) {
                int src = sp[k], dst = dp[k];
                int pos = atomicAdd(&cnt[dst], 1);
                if (pos < CAP) bucket[(long)dst * CAP + pos] = (unsigned short)src;
                else {
                    int o = atomicAdd(ovcnt, 1);
                    if (o < OV_CAP) { ovlist[o * 2] = src; ovlist[o * 2 + 1] = dst; }
                }
            }
        } else {
            for (int k = 0; k < 16; k++) {
                long e = base + k;
                if (e < EE) {
                    int src = ei[e], dst = ei[EE + e];
                    int pos = atomicAdd(&cnt[dst], 1);
                    if (pos < CAP) bucket[(long)dst * CAP + pos] = (unsigned short)src;
                    else {
                        int o = atomicAdd(ovcnt, 1);
                        if (o < OV_CAP) { ovlist[o * 2] = src; ovlist[o * 2 + 1] = dst; }
                    }
                }
            }
        }
    } else {
        gemm_core<false, false, true>(x, w1, nullptr, h, NN, HIDC, INC,
                                      blockIdx.x - BUILD_BLOCKS, 0, As, Bs);
    }
}

// out = r2 @ w2^T + b2 (A already bf16)
__global__ __launch_bounds__(256) void gemm2_k(
    const short* __restrict__ r2, const float* __restrict__ w2,
    const float* __restrict__ b2, float* __restrict__ out)
{
    __shared__ short As[64][72];
    __shared__ short Bs[128][72];
    gemm_core<true, true, false>(r2, w2, b2, out, NN, OUTC, HIDC,
                                 blockIdx.x, blockIdx.y, As, Bs);
}

// ---------------------------------------------------------------------------
// Gather: out_row[n] = sum_{e->n} hsrc[src_e] (fp32 acc). 16 lanes/node,
// 16B loads/lane. RELU: also writes raw fp32 sum (agg) + bf16 relu(sum+bias).
template<bool RELU>
__global__ __launch_bounds__(256) void gather_k(
    const short* __restrict__ hsrc, const unsigned short* __restrict__ bucket,
    const int* __restrict__ cnt, const float* __restrict__ bias,
    float* __restrict__ aggf, short* __restrict__ rout)
{
    int t = threadIdx.x;
    int node = blockIdx.x * 16 + (t >> 4);
    int c8 = t & 15;
    if (node >= NN) return;
    int m = cnt[node]; if (m > CAP) m = CAP;
    const unsigned short* bk = bucket + (long)node * CAP;
    float acc[8];
#pragma unroll
    for (int k = 0; k < 8; k++) acc[k] = 0.f;
    int j = 0;
    for (; j + 4 <= m; j += 4) {
        int s0 = bk[j], s1 = bk[j + 1], s2 = bk[j + 2], s3 = bk[j + 3];
        bf16x8 v0 = *(const bf16x8*)&hsrc[((long)s0 << 7) + c8 * 8];
        bf16x8 v1 = *(const bf16x8*)&hsrc[((long)s1 << 7) + c8 * 8];
        bf16x8 v2 = *(const bf16x8*)&hsrc[((long)s2 << 7) + c8 * 8];
        bf16x8 v3 = *(const bf16x8*)&hsrc[((long)s3 << 7) + c8 * 8];
#pragma unroll
        for (int k = 0; k < 8; k++)
            acc[k] += bf2f(v0[k]) + bf2f(v1[k]) + bf2f(v2[k]) + bf2f(v3[k]);
    }
    for (; j < m; j++) {
        int s0 = bk[j];
        bf16x8 v0 = *(const bf16x8*)&hsrc[((long)s0 << 7) + c8 * 8];
#pragma unroll
        for (int k = 0; k < 8; k++) acc[k] += bf2f(v0[k]);
    }
    if (RELU) {
        *(float4*)&aggf[((long)node << 7) + c8 * 8] =
            make_float4(acc[0], acc[1], acc[2], acc[3]);
        *(float4*)&aggf[((long)node << 7) + c8 * 8 + 4] =
            make_float4(acc[4], acc[5], acc[6], acc[7]);
        bf16x8 o;
#pragma unroll
        for (int k = 0; k < 8; k++)
            o[k] = f2bf(fmaxf(acc[k] + bias[c8 * 8 + k], 0.f));
        *(bf16x8*)&rout[((long)node << 7) + c8 * 8] = o;
    } else {
        bf16x8 o;
#pragma unroll
        for (int k = 0; k < 8; k++) o[k] = f2bf(acc[k]);
        *(bf16x8*)&rout[((long)node << 7) + c8 * 8] = o;
    }
}

// ---------------------------------------------------------------------------
// Overflow fixups (single block, expected n==0). Exactness preserved.
__global__ __launch_bounds__(128) void ovfix1_k(
    const short* __restrict__ h, const float* __restrict__ b1,
    const int* __restrict__ ovcnt, const int* __restrict__ ovlist,
    float* __restrict__ agg1, short* __restrict__ r)
{
    int n = *ovcnt; if (n > OV_CAP) n = OV_CAP;
    int c = threadIdx.x;                      // one channel per thread
    for (int i = 0; i < n; i++) {
        int src = ovlist[i * 2], dst = ovlist[i * 2 + 1];
        agg1[(long)dst * 128 + c] += bf2f(h[(long)src * 128 + c]);
    }
    __syncthreads();
    for (int i = 0; i < n; i++) {
        int dst = ovlist[i * 2 + 1];
        r[(long)dst * 128 + c] =
            f2bf(fmaxf(agg1[(long)dst * 128 + c] + b1[c], 0.f));
    }
}

__global__ __launch_bounds__(128) void ovfix2_k(
    const short* __restrict__ r, const unsigned short* __restrict__ bucket,
    const int* __restrict__ cnt, const int* __restrict__ ovcnt,
    const int* __restrict__ ovlist, short* __restrict__ r2)
{
    int n = *ovcnt; if (n > OV_CAP) n = OV_CAP;
    int c = threadIdx.x;
    for (int i = 0; i < n; i++) {
        int dst = ovlist[i * 2 + 1];
        bool dup = false;                     // uniform across threads
        for (int i2 = 0; i2 < i; i2++)
            if (ovlist[i2 * 2 + 1] == dst) { dup = true; break; }
        if (dup) continue;
        int m = cnt[dst]; if (m > CAP) m = CAP;
        const unsigned short* bk = bucket + (long)dst * CAP;
        float acc = 0.f;
        for (int j = 0; j < m; j++)
            acc += bf2f(r[(long)bk[j] * 128 + c]);
        for (int i2 = 0; i2 < n; i2++)
            if (ovlist[i2 * 2 + 1] == dst)
                acc += bf2f(r[(long)ovlist[i2 * 2] * 128 + c]);
        r2[(long)dst * 128 + c] = f2bf(acc);
    }
}

extern "C" void kernel_launch(void* const* d_in, const int* in_sizes, int n_in,
                              void* d_out, int out_size, void* d_ws, size_t ws_size,
                              hipStream_t stream) {
    const float* x  = (const float*)d_in[0];
    const int*   ei = (const int*)d_in[1];
    const float* w1 = (const float*)d_in[2];
    const float* b1 = (const float*)d_in[3];
    const float* w2 = (const float*)d_in[4];
    const float* b2 = (const float*)d_in[5];
    float* out = (float*)d_out;

    char* ws = (char*)d_ws;
    size_t off = 0;
    short* h    = (short*)(ws + off); off += (size_t)NN * HIDC * 2;          // 12.8 MB
    float* agg1 = (float*)(ws + off); off += (size_t)NN * HIDC * 4;          // 25.6 MB
    short* r    = (short*)(ws + off); off += (size_t)NN * HIDC * 2;          // 12.8 MB
    short* r2   = (short*)(ws + off); off += (size_t)NN * HIDC * 2;          // 12.8 MB
    unsigned short* bucket = (unsigned short*)(ws + off);
    off += (size_t)NN * CAP * 2;                                             // 6.4 MB
    int* cnt    = (int*)(ws + off);   off += (size_t)NN * 4;                 // 0.2 MB
    int* ovcnt  = (int*)(ws + off);   off += 256;
    int* ovlist = (int*)(ws + off);   off += (size_t)OV_CAP * 2 * 4;         // 0.5 MB

    // zero cnt + ovcnt in one memset (contiguous)
    hipMemsetAsync(cnt, 0, (size_t)NN * 4 + 4, stream);

    dim3 blk(256);

    // build buckets (blocks 0..195) || h = bf16(x @ w1^T) (blocks 196..977)
    fat_build_gemm1<<<dim3(BUILD_BLOCKS + GB1), blk, 0, stream>>>(
        ei, cnt, bucket, ovcnt, ovlist, x, w1, h);

    // agg1 = A*h (raw fp32) ; r = bf16(relu(agg1 + b1))
    gather_k<true><<<dim3(3125), blk, 0, stream>>>(h, bucket, cnt, b1, agg1, r);
    ovfix1_k<<<dim3(1), dim3(128), 0, stream>>>(h, b1, ovcnt, ovlist, agg1, r);

    // r2 = bf16(A*r)   (identical numerics to fp32 agg2 + gemm2 bf16 staging)
    gather_k<false><<<dim3(3125), blk, 0, stream>>>(r, bucket, cnt, nullptr, nullptr, r2);
    ovfix2_k<<<dim3(1), dim3(128), 0, stream>>>(r, bucket, cnt, ovcnt, ovlist, r2);

    // out = r2 @ w2^T + b2
    gemm2_k<<<dim3(GB1, 2), blk, 0, stream>>>(r2, w2, b2, out);
}